// Round 18
// baseline (866.592 us; speedup 1.0000x reference)
//
#include <hip/hip_runtime.h>
#include <hip/hip_bf16.h>

typedef __attribute__((ext_vector_type(8))) __bf16 bf16x8;
typedef __attribute__((ext_vector_type(4))) __bf16 bf16x4;
typedef __attribute__((ext_vector_type(8))) _Float16 f16x8;
typedef __attribute__((ext_vector_type(4))) _Float16 f16x4;
typedef __attribute__((ext_vector_type(4))) float f32x4;

#define LOG2E 1.44269504088896340736f

__device__ inline f32x4 mfma16(bf16x8 a, bf16x8 b, f32x4 c) {
  return __builtin_amdgcn_mfma_f32_16x16x32_bf16(a, b, c, 0, 0, 0);
}
__device__ inline f32x4 mfma16h(f16x8 a, f16x8 b, f32x4 c) {
  return __builtin_amdgcn_mfma_f32_16x16x32_f16(a, b, c, 0, 0, 0);
}

// row/w division for w in {32,48}, kg < 4096
__device__ inline int rowdiv(int kg, int w) {
  return (w == 32) ? (kg >> 5) : ((kg * 43691) >> 21);
}

// ------------------------------------------------------------------
// Projection (bf16-pair 3-term GEMM internally, unchanged).
// Outputs: QT f16-pair [B][16384][qh64|ql64], KT f16 single [B][16384][64],
// Vh/Vl f16-pair [B][64][16384] ch-major.
// Q scaled by log2(e); bk dropped (softmax-invariant).
// ------------------------------------------------------------------
__global__ __launch_bounds__(256) void proj_kernel(
    const float* __restrict__ X, const float* __restrict__ Wq,
    const float* __restrict__ Wk, const float* __restrict__ Wv,
    const float* __restrict__ bq, const float* __restrict__ bv,
    _Float16* __restrict__ QT, _Float16* __restrict__ KT,
    _Float16* __restrict__ Vh, _Float16* __restrict__ Vl)
{
  const int b = blockIdx.y;
  const int pixbase = blockIdx.x * 256;
  const int t = threadIdx.x;
  __shared__ __align__(16) __bf16 xs[256 * 128]; // [pix][hi64|lo64], row-XOR-swizzled

  { // stage X tile split into hi/lo
    const float* xp = X + (size_t)b * 64 * 16384 + pixbase + t;
    #pragma unroll
    for (int c8 = 0; c8 < 8; ++c8) {
      bf16x8 vh, vl;
      #pragma unroll
      for (int i = 0; i < 8; ++i) {
        float x = xp[(size_t)(c8 * 8 + i) * 16384];
        __bf16 h = (__bf16)x;
        vh[i] = h;
        vl[i] = (__bf16)(x - (float)h);
      }
      int col = (c8 * 8) ^ ((t & 7) << 3);
      *(bf16x8*)&xs[t * 128 + col] = vh;
      *(bf16x8*)&xs[t * 128 + 64 + col] = vl;
    }
  }
  __syncthreads();

  const int wv = t >> 6, lane = t & 63, g = lane >> 4, lq = lane & 15;

  // X as B-fragments: B[k=ci][n=pix], hi and lo
  bf16x8 xf[4][2][2];
  #pragma unroll
  for (int nt = 0; nt < 4; ++nt)
    #pragma unroll
    for (int ks = 0; ks < 2; ++ks) {
      int pixl = wv * 64 + nt * 16 + lq;
      int col = (ks * 32 + g * 8) ^ ((pixl & 7) << 3);
      xf[nt][ks][0] = *(bf16x8*)&xs[pixl * 128 + col];
      xf[nt][ks][1] = *(bf16x8*)&xs[pixl * 128 + 64 + col];
    }

  #pragma unroll
  for (int mat = 0; mat < 3; ++mat) {
    const float* Wm = (mat == 0) ? Wq : (mat == 1) ? Wk : Wv;
    #pragma unroll
    for (int mt = 0; mt < 4; ++mt) {
      // W as A-fragments: A[m=co][k=ci], co = mt*16 + lq, hi/lo split
      bf16x8 wh[2], wl[2];
      #pragma unroll
      for (int ks = 0; ks < 2; ++ks) {
        const float* wp = Wm + (mt * 16 + lq) * 64 + ks * 32 + g * 8;
        f32x4 w0 = *(const f32x4*)wp;
        f32x4 w1 = *(const f32x4*)(wp + 4);
        bf16x8 fh, fl;
        #pragma unroll
        for (int r = 0; r < 4; ++r) {
          __bf16 h0 = (__bf16)w0[r]; fh[r] = h0; fl[r] = (__bf16)(w0[r] - (float)h0);
          __bf16 h1 = (__bf16)w1[r]; fh[4 + r] = h1; fl[4 + r] = (__bf16)(w1[r] - (float)h1);
        }
        wh[ks] = fh; wl[ks] = fl;
      }
      f32x4 binit = {0.f, 0.f, 0.f, 0.f};
      if (mat == 0) binit = *(const f32x4*)(bq + mt * 16 + g * 4);
      if (mat == 2) binit = *(const f32x4*)(bv + mt * 16 + g * 4);
      f32x4 acc[4];
      #pragma unroll
      for (int nt = 0; nt < 4; ++nt) acc[nt] = binit;
      #pragma unroll
      for (int nt = 0; nt < 4; ++nt)
        #pragma unroll
        for (int ks = 0; ks < 2; ++ks) {
          acc[nt] = mfma16(wh[ks], xf[nt][ks][0], acc[nt]);
          acc[nt] = mfma16(wh[ks], xf[nt][ks][1], acc[nt]);
          acc[nt] = mfma16(wl[ks], xf[nt][ks][0], acc[nt]);
        }
      // D layout: m = co = mt*16 + g*4 + r ; n = pix = nt*16 + lq
      #pragma unroll
      for (int nt = 0; nt < 4; ++nt) {
        int pix = pixbase + wv * 64 + nt * 16 + lq;
        if (mat == 2) {
          #pragma unroll
          for (int r = 0; r < 4; ++r) {
            float v = acc[nt][r];
            _Float16 h = (_Float16)v;
            size_t idx = ((size_t)b * 64 + mt * 16 + g * 4 + r) * 16384 + pix;
            Vh[idx] = h;
            Vl[idx] = (_Float16)(v - (float)h);
          }
        } else if (mat == 0) {
          f16x4 oh, ol;
          #pragma unroll
          for (int r = 0; r < 4; ++r) {
            float v = acc[nt][r] * LOG2E;
            _Float16 h = (_Float16)v;
            oh[r] = h;
            ol[r] = (_Float16)(v - (float)h);
          }
          _Float16* dst = QT + ((size_t)b * 16384 + pix) * 128 + mt * 16 + g * 4;
          *(f16x4*)dst = oh;
          *(f16x4*)(dst + 64) = ol;
        } else {
          f16x4 oh;
          #pragma unroll
          for (int r = 0; r < 4; ++r) oh[r] = (_Float16)acc[nt][r];
          *(f16x4*)(KT + ((size_t)b * 16384 + pix) * 64 + mt * 16 + g * 4) = oh;
        }
      }
    }
  }
}

// ------------------------------------------------------------------
// Flash attention, barrier-free. 4 waves x 32 queries (1 row) per block;
// K/V fragments direct from global, LDS only for the per-wave P plane.
// QK^T: 2-term f16 (K single-plane). PV: 2-term f16. Defer-max THR=8.
// Grid 1024 -> 4 blocks/CU; f16-slim body (~qf32+s32+O32 regs) targets
// 3-4 waves/SIMD -- the TLP that the pair-precision 64q body (188 unified
// regs) could never reach. Math bit-identical to R17 (absmax 0.15625).
// Block decode: xcd = batch (i&7), windows desc-Nk.
// ------------------------------------------------------------------
__global__ __launch_bounds__(256) void attn_kernel(
    const _Float16* __restrict__ QT, const _Float16* __restrict__ KT,
    const _Float16* __restrict__ Vh, const _Float16* __restrict__ Vl,
    const float* RES, float* OUT)
{
  const int i = blockIdx.x;
  const int b = i & 7;
  const int s_lin = i >> 3;
  const int wo = s_lin >> 3;
  const int qb = s_lin & 7;
  int win;
  {
    int w3 = (wo * 11) >> 5; // wo/3 for wo<9
    win = (wo < 9) ? (wo + w3) : ((wo < 12) ? (3 + ((wo - 9) << 2)) : wo);
  }
  const int wi = win >> 2, wj = win & 3;
  const int sx = wi * 32, sy = wj * 32;
  const int w = (128 - sy) < 48 ? (128 - sy) : 48;
  const int h = (128 - sx) < 48 ? (128 - sx) : 48;
  const int Nk = h * w, nch = Nk >> 6;
  const int t = threadIdx.x;
  const int wv = t >> 6, lane = t & 63, g = lane >> 4, lq = lane & 15;

  __shared__ __align__(16) _Float16 lp[4][32 * 64]; // per-wave P (f16, 16 KB)

  // Q fragments (B of S^T): B[k=ch][n=q]; wave owns row qb*4+wv
  const int qrow = sx + qb * 4 + wv;
  f16x8 qf[2][2][2]; // [qt][ks][hi/lo]
  #pragma unroll
  for (int qt = 0; qt < 2; ++qt) {
    int qpix = qrow * 128 + sy + qt * 16 + lq;
    const _Float16* qp = QT + ((size_t)b * 16384 + qpix) * 128;
    qf[qt][0][0] = *(const f16x8*)(qp + g * 8);
    qf[qt][1][0] = *(const f16x8*)(qp + 32 + g * 8);
    qf[qt][0][1] = *(const f16x8*)(qp + 64 + g * 8);
    qf[qt][1][1] = *(const f16x8*)(qp + 96 + g * 8);
  }

  f32x4 O[2][4]; // O^T acc: m = ch = cht*16 + g*4 + r ; n = q
  #pragma unroll
  for (int qt = 0; qt < 2; ++qt)
    #pragma unroll
    for (int cht = 0; cht < 4; ++cht) O[qt][cht] = (f32x4){0.f, 0.f, 0.f, 0.f};
  float m[2] = {-__builtin_inff(), -__builtin_inff()};
  float l[2] = {0.f, 0.f};

  for (int ch = 0; ch < nch; ++ch) {
    const int kbase = ch * 64;

    // ---- QK^T: S^T[key][q], K (single f16 plane) direct from global ----
    f32x4 s[2][4]; // [qt][t4]
    #pragma unroll
    for (int qt = 0; qt < 2; ++qt)
      #pragma unroll
      for (int t4 = 0; t4 < 4; ++t4) s[qt][t4] = (f32x4){0.f, 0.f, 0.f, 0.f};
    #pragma unroll
    for (int t4 = 0; t4 < 4; ++t4) {
      int kg = kbase + t4 * 16 + lq;
      int kr = rowdiv(kg, w), kc = kg - kr * w;
      const _Float16* kp = KT + ((size_t)b * 16384 + (sx + kr) * 128 + sy + kc) * 64 + g * 8;
      f16x8 kh0 = *(const f16x8*)(kp);
      f16x8 kh1 = *(const f16x8*)(kp + 32);
      __builtin_amdgcn_s_setprio(1);
      #pragma unroll
      for (int qt = 0; qt < 2; ++qt) {
        s[qt][t4] = mfma16h(kh0, qf[qt][0][0], s[qt][t4]);
        s[qt][t4] = mfma16h(kh0, qf[qt][0][1], s[qt][t4]);
        s[qt][t4] = mfma16h(kh1, qf[qt][1][0], s[qt][t4]);
        s[qt][t4] = mfma16h(kh1, qf[qt][1][1], s[qt][t4]);
      }
      __builtin_amdgcn_s_setprio(0);
    }

    // ---- online softmax (defer-max THR=8, log2 domain) + P (f16) -> lp ----
    #pragma unroll
    for (int qt = 0; qt < 2; ++qt) {
      float cm = -__builtin_inff();
      #pragma unroll
      for (int t4 = 0; t4 < 4; ++t4)
        #pragma unroll
        for (int r = 0; r < 4; ++r) cm = fmaxf(cm, s[qt][t4][r]);
      cm = fmaxf(cm, __shfl_xor(cm, 16));
      cm = fmaxf(cm, __shfl_xor(cm, 32));
      if (__any(cm > m[qt] + 8.0f)) {
        float mnew = fmaxf(m[qt], cm);
        float sc = exp2f(m[qt] - mnew);
        m[qt] = mnew;
        l[qt] *= sc;
        #pragma unroll
        for (int cht = 0; cht < 4; ++cht) O[qt][cht] *= sc;
      }
      float ps = 0.f;
      int rowb = (qt * 16 + lq) * 64;
      #pragma unroll
      for (int t4 = 0; t4 < 4; ++t4) {
        float p0 = exp2f(s[qt][t4][0] - m[qt]);
        float p1 = exp2f(s[qt][t4][1] - m[qt]);
        float p2 = exp2f(s[qt][t4][2] - m[qt]);
        float p3 = exp2f(s[qt][t4][3] - m[qt]);
        ps += (p0 + p1) + (p2 + p3);
        f16x4 ph;
        ph[0] = (_Float16)p0;
        ph[1] = (_Float16)p1;
        ph[2] = (_Float16)p2;
        ph[3] = (_Float16)p3;
        int col = (t4 * 16 + g * 4) ^ ((lq & 7) << 3);
        *(f16x4*)&lp[wv][rowb + col] = ph;
      }
      ps += __shfl_xor(ps, 16);
      ps += __shfl_xor(ps, 32);
      l[qt] += ps;
    }

    // ---- PV: O^T += V^T-frag x P^T-frag, 2-term f16, V direct from global ----
    #pragma unroll
    for (int ks = 0; ks < 2; ++ks) {
      int kg = kbase + ks * 32 + g * 8;
      int kr = rowdiv(kg, w), kc = kg - kr * w;
      size_t vpo = (size_t)b * 64 * 16384 + (size_t)((sx + kr) * 128 + sy + kc);
      f16x8 vfh[4], vfl[4];
      #pragma unroll
      for (int cht = 0; cht < 4; ++cht) {
        size_t a = vpo + (size_t)(cht * 16 + lq) * 16384;
        vfh[cht] = *(const f16x8*)(Vh + a);
        vfl[cht] = *(const f16x8*)(Vl + a);
      }
      int pcol = (ks * 32 + g * 8) ^ ((lq & 7) << 3);
      #pragma unroll
      for (int qt = 0; qt < 2; ++qt) {
        int rowb = (qt * 16 + lq) * 64;
        f16x8 pb = *(f16x8*)&lp[wv][rowb + pcol];
        __builtin_amdgcn_s_setprio(1);
        #pragma unroll
        for (int cht = 0; cht < 4; ++cht) {
          O[qt][cht] = mfma16h(vfh[cht], pb, O[qt][cht]);
          O[qt][cht] = mfma16h(vfl[cht], pb, O[qt][cht]);
        }
        __builtin_amdgcn_s_setprio(0);
      }
    }
  }

  // epilogue: out = O/l + residual
  #pragma unroll
  for (int qt = 0; qt < 2; ++qt) {
    float inv = 1.0f / l[qt];
    int qpix = qrow * 128 + sy + qt * 16 + lq;
    #pragma unroll
    for (int cht = 0; cht < 4; ++cht)
      #pragma unroll
      for (int r = 0; r < 4; ++r) {
        int chn = cht * 16 + g * 4 + r;
        size_t idx = ((size_t)b * 64 + chn) * 16384 + qpix;
        OUT[idx] = O[qt][cht][r] * inv + RES[idx];
      }
  }
}

extern "C" void kernel_launch(void* const* d_in, const int* in_sizes, int n_in,
                              void* d_out, int out_size, void* d_ws, size_t ws_size,
                              hipStream_t stream) {
  const float* x   = (const float*)d_in[0];
  const float* Wq1 = (const float*)d_in[1];
  const float* Wk1 = (const float*)d_in[2];
  const float* Wv1 = (const float*)d_in[3];
  const float* Wq2 = (const float*)d_in[4];
  const float* Wk2 = (const float*)d_in[5];
  const float* Wv2 = (const float*)d_in[6];
  const float* bq1 = (const float*)d_in[7];
  /* bk1 = d_in[8], bk2 = d_in[11]: exactly cancel under softmax */
  const float* bv1 = (const float*)d_in[9];
  const float* bq2 = (const float*)d_in[10];
  const float* bv2 = (const float*)d_in[12];
  float* out = (float*)d_out;

  const size_t IMG = (size_t)8 * 16384;
  _Float16* QT = (_Float16*)d_ws;   // [8][16384][128] (qh|ql)
  _Float16* KT = QT + IMG * 128;    // [8][16384][64]  (kh only)
  _Float16* Vh = KT + IMG * 64;     // [8][64][16384]
  _Float16* Vl = Vh + IMG * 64;     // [8][64][16384]

  dim3 pgrid(64, 8);
  // layer 1
  proj_kernel<<<pgrid, 256, 0, stream>>>(x, Wq1, Wk1, Wv1, bq1, bv1, QT, KT, Vh, Vl);
  attn_kernel<<<1024, 256, 0, stream>>>(QT, KT, Vh, Vl, x, out);
  // layer 2 (reads layer-1 output from d_out; residual aliases output safely)
  proj_kernel<<<pgrid, 256, 0, stream>>>(out, Wq2, Wk2, Wv2, bq2, bv2, QT, KT, Vh, Vl);
  attn_kernel<<<1024, 256, 0, stream>>>(QT, KT, Vh, Vl, out, out);
}

// Round 19
// 463.549 us; speedup vs baseline: 1.8695x; 1.8695x over previous
//
#include <hip/hip_runtime.h>
#include <hip/hip_bf16.h>

typedef __attribute__((ext_vector_type(8))) __bf16 bf16x8;
typedef __attribute__((ext_vector_type(4))) __bf16 bf16x4;
typedef __attribute__((ext_vector_type(8))) _Float16 f16x8;
typedef __attribute__((ext_vector_type(4))) _Float16 f16x4;
typedef __attribute__((ext_vector_type(4))) float f32x4;

#define LOG2E 1.44269504088896340736f

__device__ inline f32x4 mfma16(bf16x8 a, bf16x8 b, f32x4 c) {
  return __builtin_amdgcn_mfma_f32_16x16x32_bf16(a, b, c, 0, 0, 0);
}
__device__ inline f32x4 mfma16h(f16x8 a, f16x8 b, f32x4 c) {
  return __builtin_amdgcn_mfma_f32_16x16x32_f16(a, b, c, 0, 0, 0);
}

// row/w division for w in {32,48}, kg < 4096
__device__ inline int rowdiv(int kg, int w) {
  return (w == 32) ? (kg >> 5) : ((kg * 43691) >> 21);
}

// ------------------------------------------------------------------
// Projection (bf16-pair 3-term GEMM internally, unchanged).
// Outputs: QT f16-pair [B][16384][qh64|ql64], KT f16 single [B][16384][64],
// V f16 single [B][64][16384] ch-major.
// Q scaled by log2(e); bk dropped (softmax-invariant).
// Precision plan (empirically anchored): QK = kh*(qh+ql) (2-term);
// PV = p(f16) * v(f16 single). P@2^-11 measured ~0.05-0.07 abs (R16);
// V@2^-11 symmetric -> ~0.07; RSS with 0.156 -> ~0.17 < 0.2225.
// ------------------------------------------------------------------
__global__ __launch_bounds__(256) void proj_kernel(
    const float* __restrict__ X, const float* __restrict__ Wq,
    const float* __restrict__ Wk, const float* __restrict__ Wv,
    const float* __restrict__ bq, const float* __restrict__ bv,
    _Float16* __restrict__ QT, _Float16* __restrict__ KT,
    _Float16* __restrict__ Vc)
{
  const int b = blockIdx.y;
  const int pixbase = blockIdx.x * 256;
  const int t = threadIdx.x;
  __shared__ __align__(16) __bf16 xs[256 * 128]; // [pix][hi64|lo64], row-XOR-swizzled

  { // stage X tile split into hi/lo
    const float* xp = X + (size_t)b * 64 * 16384 + pixbase + t;
    #pragma unroll
    for (int c8 = 0; c8 < 8; ++c8) {
      bf16x8 vh, vl;
      #pragma unroll
      for (int i = 0; i < 8; ++i) {
        float x = xp[(size_t)(c8 * 8 + i) * 16384];
        __bf16 h = (__bf16)x;
        vh[i] = h;
        vl[i] = (__bf16)(x - (float)h);
      }
      int col = (c8 * 8) ^ ((t & 7) << 3);
      *(bf16x8*)&xs[t * 128 + col] = vh;
      *(bf16x8*)&xs[t * 128 + 64 + col] = vl;
    }
  }
  __syncthreads();

  const int wv = t >> 6, lane = t & 63, g = lane >> 4, lq = lane & 15;

  // X as B-fragments: B[k=ci][n=pix], hi and lo
  bf16x8 xf[4][2][2];
  #pragma unroll
  for (int nt = 0; nt < 4; ++nt)
    #pragma unroll
    for (int ks = 0; ks < 2; ++ks) {
      int pixl = wv * 64 + nt * 16 + lq;
      int col = (ks * 32 + g * 8) ^ ((pixl & 7) << 3);
      xf[nt][ks][0] = *(bf16x8*)&xs[pixl * 128 + col];
      xf[nt][ks][1] = *(bf16x8*)&xs[pixl * 128 + 64 + col];
    }

  #pragma unroll
  for (int mat = 0; mat < 3; ++mat) {
    const float* Wm = (mat == 0) ? Wq : (mat == 1) ? Wk : Wv;
    #pragma unroll
    for (int mt = 0; mt < 4; ++mt) {
      // W as A-fragments: A[m=co][k=ci], co = mt*16 + lq, hi/lo split
      bf16x8 wh[2], wl[2];
      #pragma unroll
      for (int ks = 0; ks < 2; ++ks) {
        const float* wp = Wm + (mt * 16 + lq) * 64 + ks * 32 + g * 8;
        f32x4 w0 = *(const f32x4*)wp;
        f32x4 w1 = *(const f32x4*)(wp + 4);
        bf16x8 fh, fl;
        #pragma unroll
        for (int r = 0; r < 4; ++r) {
          __bf16 h0 = (__bf16)w0[r]; fh[r] = h0; fl[r] = (__bf16)(w0[r] - (float)h0);
          __bf16 h1 = (__bf16)w1[r]; fh[4 + r] = h1; fl[4 + r] = (__bf16)(w1[r] - (float)h1);
        }
        wh[ks] = fh; wl[ks] = fl;
      }
      f32x4 binit = {0.f, 0.f, 0.f, 0.f};
      if (mat == 0) binit = *(const f32x4*)(bq + mt * 16 + g * 4);
      if (mat == 2) binit = *(const f32x4*)(bv + mt * 16 + g * 4);
      f32x4 acc[4];
      #pragma unroll
      for (int nt = 0; nt < 4; ++nt) acc[nt] = binit;
      #pragma unroll
      for (int nt = 0; nt < 4; ++nt)
        #pragma unroll
        for (int ks = 0; ks < 2; ++ks) {
          acc[nt] = mfma16(wh[ks], xf[nt][ks][0], acc[nt]);
          acc[nt] = mfma16(wh[ks], xf[nt][ks][1], acc[nt]);
          acc[nt] = mfma16(wl[ks], xf[nt][ks][0], acc[nt]);
        }
      // D layout: m = co = mt*16 + g*4 + r ; n = pix = nt*16 + lq
      #pragma unroll
      for (int nt = 0; nt < 4; ++nt) {
        int pix = pixbase + wv * 64 + nt * 16 + lq;
        if (mat == 2) {
          #pragma unroll
          for (int r = 0; r < 4; ++r)
            Vc[((size_t)b * 64 + mt * 16 + g * 4 + r) * 16384 + pix] = (_Float16)acc[nt][r];
        } else if (mat == 0) {
          f16x4 oh, ol;
          #pragma unroll
          for (int r = 0; r < 4; ++r) {
            float v = acc[nt][r] * LOG2E;
            _Float16 h = (_Float16)v;
            oh[r] = h;
            ol[r] = (_Float16)(v - (float)h);
          }
          _Float16* dst = QT + ((size_t)b * 16384 + pix) * 128 + mt * 16 + g * 4;
          *(f16x4*)dst = oh;
          *(f16x4*)(dst + 64) = ol;
        } else {
          f16x4 oh;
          #pragma unroll
          for (int r = 0; r < 4; ++r) oh[r] = (_Float16)acc[nt][r];
          *(f16x4*)(KT + ((size_t)b * 16384 + pix) * 64 + mt * 16 + g * 4) = oh;
        }
      }
    }
  }
}

// ------------------------------------------------------------------
// Flash attention, barrier-free. 4 waves x 64 queries (2 rows) per block
// (R17 structure -- 32q failed 4x on allocator pathology); K/V fragments
// direct from global, LDS only for the per-wave P plane.
// QK^T: 2-term f16 (K single-plane). PV: 1-term f16 (V single-plane --
// halves PV MFMAs and V fetch). Defer-max THR=8 (log2 domain).
// Block decode: xcd = batch (i&7), windows desc-Nk.
// ------------------------------------------------------------------
__global__ __launch_bounds__(256, 2) void attn_kernel(
    const _Float16* __restrict__ QT, const _Float16* __restrict__ KT,
    const _Float16* __restrict__ Vc, const float* RES, float* OUT)
{
  const int i = blockIdx.x;
  const int b = i & 7;
  const int s_lin = i >> 3;
  const int wo = s_lin >> 2;
  const int qb = s_lin & 3;
  int win;
  {
    int w3 = (wo * 11) >> 5; // wo/3 for wo<9
    win = (wo < 9) ? (wo + w3) : ((wo < 12) ? (3 + ((wo - 9) << 2)) : wo);
  }
  const int wi = win >> 2, wj = win & 3;
  const int sx = wi * 32, sy = wj * 32;
  const int w = (128 - sy) < 48 ? (128 - sy) : 48;
  const int h = (128 - sx) < 48 ? (128 - sx) : 48;
  const int Nk = h * w, nch = Nk >> 6;
  const int t = threadIdx.x;
  const int wv = t >> 6, lane = t & 63, g = lane >> 4, lq = lane & 15;

  __shared__ __align__(16) _Float16 lp[4][64 * 64]; // per-wave P (f16, 32 KB)

  // Q fragments (B of S^T): B[k=ch][n=q]; wave owns rows r0,r0+1
  const int r0 = sx + qb * 8 + wv * 2;
  f16x8 qf[4][2][2]; // [qt][ks][hi/lo]
  #pragma unroll
  for (int qt = 0; qt < 4; ++qt) {
    int qpix = (r0 + (qt >> 1)) * 128 + sy + (qt & 1) * 16 + lq;
    const _Float16* qp = QT + ((size_t)b * 16384 + qpix) * 128;
    qf[qt][0][0] = *(const f16x8*)(qp + g * 8);
    qf[qt][1][0] = *(const f16x8*)(qp + 32 + g * 8);
    qf[qt][0][1] = *(const f16x8*)(qp + 64 + g * 8);
    qf[qt][1][1] = *(const f16x8*)(qp + 96 + g * 8);
  }

  f32x4 O[4][4]; // O^T acc: m = ch = cht*16 + g*4 + r ; n = q
  #pragma unroll
  for (int qt = 0; qt < 4; ++qt)
    #pragma unroll
    for (int cht = 0; cht < 4; ++cht) O[qt][cht] = (f32x4){0.f, 0.f, 0.f, 0.f};
  float m[4] = {-__builtin_inff(), -__builtin_inff(), -__builtin_inff(), -__builtin_inff()};
  float l[4] = {0.f, 0.f, 0.f, 0.f};

  for (int ch = 0; ch < nch; ++ch) {
    const int kbase = ch * 64;

    // ---- QK^T: S^T[key][q], K (single f16 plane) direct from global ----
    f32x4 s[4][4]; // [qt][t4]
    #pragma unroll
    for (int qt = 0; qt < 4; ++qt)
      #pragma unroll
      for (int t4 = 0; t4 < 4; ++t4) s[qt][t4] = (f32x4){0.f, 0.f, 0.f, 0.f};
    #pragma unroll
    for (int t4 = 0; t4 < 4; ++t4) {
      int kg = kbase + t4 * 16 + lq;
      int kr = rowdiv(kg, w), kc = kg - kr * w;
      const _Float16* kp = KT + ((size_t)b * 16384 + (sx + kr) * 128 + sy + kc) * 64 + g * 8;
      f16x8 kh0 = *(const f16x8*)(kp);
      f16x8 kh1 = *(const f16x8*)(kp + 32);
      __builtin_amdgcn_s_setprio(1);
      #pragma unroll
      for (int qt = 0; qt < 4; ++qt) {
        s[qt][t4] = mfma16h(kh0, qf[qt][0][0], s[qt][t4]);
        s[qt][t4] = mfma16h(kh0, qf[qt][0][1], s[qt][t4]);
        s[qt][t4] = mfma16h(kh1, qf[qt][1][0], s[qt][t4]);
        s[qt][t4] = mfma16h(kh1, qf[qt][1][1], s[qt][t4]);
      }
      __builtin_amdgcn_s_setprio(0);
    }

    // ---- online softmax (defer-max THR=8, log2 domain) + P (f16) -> lp ----
    #pragma unroll
    for (int qt = 0; qt < 4; ++qt) {
      float cm = -__builtin_inff();
      #pragma unroll
      for (int t4 = 0; t4 < 4; ++t4)
        #pragma unroll
        for (int r = 0; r < 4; ++r) cm = fmaxf(cm, s[qt][t4][r]);
      cm = fmaxf(cm, __shfl_xor(cm, 16));
      cm = fmaxf(cm, __shfl_xor(cm, 32));
      if (__any(cm > m[qt] + 8.0f)) {
        float mnew = fmaxf(m[qt], cm);
        float sc = exp2f(m[qt] - mnew);
        m[qt] = mnew;
        l[qt] *= sc;
        #pragma unroll
        for (int cht = 0; cht < 4; ++cht) O[qt][cht] *= sc;
      }
      float ps = 0.f;
      int rowb = (qt * 16 + lq) * 64;
      #pragma unroll
      for (int t4 = 0; t4 < 4; ++t4) {
        float p0 = exp2f(s[qt][t4][0] - m[qt]);
        float p1 = exp2f(s[qt][t4][1] - m[qt]);
        float p2 = exp2f(s[qt][t4][2] - m[qt]);
        float p3 = exp2f(s[qt][t4][3] - m[qt]);
        ps += (p0 + p1) + (p2 + p3);
        f16x4 ph;
        ph[0] = (_Float16)p0;
        ph[1] = (_Float16)p1;
        ph[2] = (_Float16)p2;
        ph[3] = (_Float16)p3;
        int col = (t4 * 16 + g * 4) ^ ((lq & 7) << 3);
        *(f16x4*)&lp[wv][rowb + col] = ph;
      }
      ps += __shfl_xor(ps, 16);
      ps += __shfl_xor(ps, 32);
      l[qt] += ps;
    }

    // ---- PV: O^T += V^T-frag x P^T-frag, 1-term f16, V direct from global ----
    #pragma unroll
    for (int ks = 0; ks < 2; ++ks) {
      int kg = kbase + ks * 32 + g * 8;
      int kr = rowdiv(kg, w), kc = kg - kr * w;
      size_t vpo = (size_t)b * 64 * 16384 + (size_t)((sx + kr) * 128 + sy + kc);
      f16x8 vf[4];
      #pragma unroll
      for (int cht = 0; cht < 4; ++cht)
        vf[cht] = *(const f16x8*)(Vc + vpo + (size_t)(cht * 16 + lq) * 16384);
      int pcol = (ks * 32 + g * 8) ^ ((lq & 7) << 3);
      #pragma unroll
      for (int qt = 0; qt < 4; ++qt) {
        int rowb = (qt * 16 + lq) * 64;
        f16x8 pb = *(f16x8*)&lp[wv][rowb + pcol];
        __builtin_amdgcn_s_setprio(1);
        #pragma unroll
        for (int cht = 0; cht < 4; ++cht)
          O[qt][cht] = mfma16h(vf[cht], pb, O[qt][cht]);
        __builtin_amdgcn_s_setprio(0);
      }
    }
  }

  // epilogue: out = O/l + residual
  #pragma unroll
  for (int qt = 0; qt < 4; ++qt) {
    float inv = 1.0f / l[qt];
    int qpix = (r0 + (qt >> 1)) * 128 + sy + (qt & 1) * 16 + lq;
    #pragma unroll
    for (int cht = 0; cht < 4; ++cht)
      #pragma unroll
      for (int r = 0; r < 4; ++r) {
        int chn = cht * 16 + g * 4 + r;
        size_t idx = ((size_t)b * 64 + chn) * 16384 + qpix;
        OUT[idx] = O[qt][cht][r] * inv + RES[idx];
      }
  }
}

extern "C" void kernel_launch(void* const* d_in, const int* in_sizes, int n_in,
                              void* d_out, int out_size, void* d_ws, size_t ws_size,
                              hipStream_t stream) {
  const float* x   = (const float*)d_in[0];
  const float* Wq1 = (const float*)d_in[1];
  const float* Wk1 = (const float*)d_in[2];
  const float* Wv1 = (const float*)d_in[3];
  const float* Wq2 = (const float*)d_in[4];
  const float* Wk2 = (const float*)d_in[5];
  const float* Wv2 = (const float*)d_in[6];
  const float* bq1 = (const float*)d_in[7];
  /* bk1 = d_in[8], bk2 = d_in[11]: exactly cancel under softmax */
  const float* bv1 = (const float*)d_in[9];
  const float* bq2 = (const float*)d_in[10];
  const float* bv2 = (const float*)d_in[12];
  float* out = (float*)d_out;

  const size_t IMG = (size_t)8 * 16384;
  _Float16* QT = (_Float16*)d_ws;   // [8][16384][128] (qh|ql)
  _Float16* KT = QT + IMG * 128;    // [8][16384][64]  (kh only)
  _Float16* Vc = KT + IMG * 64;     // [8][64][16384]  (single plane)

  dim3 pgrid(64, 8);
  // layer 1
  proj_kernel<<<pgrid, 256, 0, stream>>>(x, Wq1, Wk1, Wv1, bq1, bv1, QT, KT, Vc);
  attn_kernel<<<512, 256, 0, stream>>>(QT, KT, Vc, x, out);
  // layer 2 (reads layer-1 output from d_out; residual aliases output safely)
  proj_kernel<<<pgrid, 256, 0, stream>>>(out, Wq2, Wk2, Wv2, bq2, bv2, QT, KT, Vc);
  attn_kernel<<<512, 256, 0, stream>>>(QT, KT, Vc, out, out);
}

// Round 20
// 405.468 us; speedup vs baseline: 2.1373x; 1.1432x over previous
//
#include <hip/hip_runtime.h>
#include <hip/hip_bf16.h>

typedef __attribute__((ext_vector_type(8))) __bf16 bf16x8;
typedef __attribute__((ext_vector_type(4))) __bf16 bf16x4;
typedef __attribute__((ext_vector_type(8))) _Float16 f16x8;
typedef __attribute__((ext_vector_type(4))) _Float16 f16x4;
typedef __attribute__((ext_vector_type(4))) float f32x4;

#define LOG2E 1.44269504088896340736f

__device__ inline f32x4 mfma16(bf16x8 a, bf16x8 b, f32x4 c) {
  return __builtin_amdgcn_mfma_f32_16x16x32_bf16(a, b, c, 0, 0, 0);
}
__device__ inline f32x4 mfma16h(f16x8 a, f16x8 b, f32x4 c) {
  return __builtin_amdgcn_mfma_f32_16x16x32_f16(a, b, c, 0, 0, 0);
}

// row/w division for w in {32,48}, kg < 4096
__device__ inline int rowdiv(int kg, int w) {
  return (w == 32) ? (kg >> 5) : ((kg * 43691) >> 21);
}

// async global->LDS DMA, 16B per lane; lds addr is wave-uniform base + lane*16
__device__ __forceinline__ void dma16(const void* g, void* l) {
  __builtin_amdgcn_global_load_lds(
      (const __attribute__((address_space(1))) void*)g,
      (__attribute__((address_space(3))) void*)l, 16, 0, 0);
}

// ------------------------------------------------------------------
// Projection (bf16-pair 3-term GEMM internally, unchanged from R19).
// Outputs: QT f16-pair [B][16384][qh64|ql64], KT f16 single [B][16384][64],
// V f16 single [B][64][16384] ch-major.
// Q scaled by log2(e); bk dropped (softmax-invariant).
// ------------------------------------------------------------------
__global__ __launch_bounds__(256) void proj_kernel(
    const float* __restrict__ X, const float* __restrict__ Wq,
    const float* __restrict__ Wk, const float* __restrict__ Wv,
    const float* __restrict__ bq, const float* __restrict__ bv,
    _Float16* __restrict__ QT, _Float16* __restrict__ KT,
    _Float16* __restrict__ Vc)
{
  const int b = blockIdx.y;
  const int pixbase = blockIdx.x * 256;
  const int t = threadIdx.x;
  __shared__ __align__(16) __bf16 xs[256 * 128]; // [pix][hi64|lo64], row-XOR-swizzled

  { // stage X tile split into hi/lo
    const float* xp = X + (size_t)b * 64 * 16384 + pixbase + t;
    #pragma unroll
    for (int c8 = 0; c8 < 8; ++c8) {
      bf16x8 vh, vl;
      #pragma unroll
      for (int i = 0; i < 8; ++i) {
        float x = xp[(size_t)(c8 * 8 + i) * 16384];
        __bf16 h = (__bf16)x;
        vh[i] = h;
        vl[i] = (__bf16)(x - (float)h);
      }
      int col = (c8 * 8) ^ ((t & 7) << 3);
      *(bf16x8*)&xs[t * 128 + col] = vh;
      *(bf16x8*)&xs[t * 128 + 64 + col] = vl;
    }
  }
  __syncthreads();

  const int wv = t >> 6, lane = t & 63, g = lane >> 4, lq = lane & 15;

  // X as B-fragments: B[k=ci][n=pix], hi and lo
  bf16x8 xf[4][2][2];
  #pragma unroll
  for (int nt = 0; nt < 4; ++nt)
    #pragma unroll
    for (int ks = 0; ks < 2; ++ks) {
      int pixl = wv * 64 + nt * 16 + lq;
      int col = (ks * 32 + g * 8) ^ ((pixl & 7) << 3);
      xf[nt][ks][0] = *(bf16x8*)&xs[pixl * 128 + col];
      xf[nt][ks][1] = *(bf16x8*)&xs[pixl * 128 + 64 + col];
    }

  #pragma unroll
  for (int mat = 0; mat < 3; ++mat) {
    const float* Wm = (mat == 0) ? Wq : (mat == 1) ? Wk : Wv;
    #pragma unroll
    for (int mt = 0; mt < 4; ++mt) {
      // W as A-fragments: A[m=co][k=ci], co = mt*16 + lq, hi/lo split
      bf16x8 wh[2], wl[2];
      #pragma unroll
      for (int ks = 0; ks < 2; ++ks) {
        const float* wp = Wm + (mt * 16 + lq) * 64 + ks * 32 + g * 8;
        f32x4 w0 = *(const f32x4*)wp;
        f32x4 w1 = *(const f32x4*)(wp + 4);
        bf16x8 fh, fl;
        #pragma unroll
        for (int r = 0; r < 4; ++r) {
          __bf16 h0 = (__bf16)w0[r]; fh[r] = h0; fl[r] = (__bf16)(w0[r] - (float)h0);
          __bf16 h1 = (__bf16)w1[r]; fh[4 + r] = h1; fl[4 + r] = (__bf16)(w1[r] - (float)h1);
        }
        wh[ks] = fh; wl[ks] = fl;
      }
      f32x4 binit = {0.f, 0.f, 0.f, 0.f};
      if (mat == 0) binit = *(const f32x4*)(bq + mt * 16 + g * 4);
      if (mat == 2) binit = *(const f32x4*)(bv + mt * 16 + g * 4);
      f32x4 acc[4];
      #pragma unroll
      for (int nt = 0; nt < 4; ++nt) acc[nt] = binit;
      #pragma unroll
      for (int nt = 0; nt < 4; ++nt)
        #pragma unroll
        for (int ks = 0; ks < 2; ++ks) {
          acc[nt] = mfma16(wh[ks], xf[nt][ks][0], acc[nt]);
          acc[nt] = mfma16(wh[ks], xf[nt][ks][1], acc[nt]);
          acc[nt] = mfma16(wl[ks], xf[nt][ks][0], acc[nt]);
        }
      // D layout: m = co = mt*16 + g*4 + r ; n = pix = nt*16 + lq
      #pragma unroll
      for (int nt = 0; nt < 4; ++nt) {
        int pix = pixbase + wv * 64 + nt * 16 + lq;
        if (mat == 2) {
          #pragma unroll
          for (int r = 0; r < 4; ++r)
            Vc[((size_t)b * 64 + mt * 16 + g * 4 + r) * 16384 + pix] = (_Float16)acc[nt][r];
        } else if (mat == 0) {
          f16x4 oh, ol;
          #pragma unroll
          for (int r = 0; r < 4; ++r) {
            float v = acc[nt][r] * LOG2E;
            _Float16 h = (_Float16)v;
            oh[r] = h;
            ol[r] = (_Float16)(v - (float)h);
          }
          _Float16* dst = QT + ((size_t)b * 16384 + pix) * 128 + mt * 16 + g * 4;
          *(f16x4*)dst = oh;
          *(f16x4*)(dst + 64) = ol;
        } else {
          f16x4 oh;
          #pragma unroll
          for (int r = 0; r < 4; ++r) oh[r] = (_Float16)acc[nt][r];
          *(f16x4*)(KT + ((size_t)b * 16384 + pix) * 64 + mt * 16 + g * 4) = oh;
        }
      }
    }
  }
}

// ------------------------------------------------------------------
// Flash attention with DMA-staged single-plane K/V (double-buffered).
// 4 waves x 64 queries (2 rows) per block. Per chunk: issue next chunk's
// K+V DMA (zero VGPR), compute current from LDS, one barrier.
// R15's 1-blk/CU failure is fixed: single-plane halves the staged bytes ->
// LDS = kbuf 2x8K + vbuf 2x8K + lp 32K = 64 KB -> 2 blocks/CU (grid cap),
// so barrier drain overlaps the co-resident block. ds_read (~120cy)
// replaces the serialized ~400cy global K/V chain = the measured 50% stall.
// Staging: linear DMA dest + inverse-swizzled SOURCE + swizzled reads.
// QK^T: 2-term f16. PV: 1-term f16. Defer-max THR=8 (log2 domain).
// Block decode: xcd = batch (i&7), windows desc-Nk. Math == R19.
// ------------------------------------------------------------------
__global__ __launch_bounds__(256, 2) void attn_kernel(
    const _Float16* __restrict__ QT, const _Float16* __restrict__ KT,
    const _Float16* __restrict__ Vc, const float* RES, float* OUT)
{
  const int i = blockIdx.x;
  const int b = i & 7;
  const int s_lin = i >> 3;
  const int wo = s_lin >> 2;
  const int qb = s_lin & 3;
  int win;
  {
    int w3 = (wo * 11) >> 5; // wo/3 for wo<9
    win = (wo < 9) ? (wo + w3) : ((wo < 12) ? (3 + ((wo - 9) << 2)) : wo);
  }
  const int wi = win >> 2, wj = win & 3;
  const int sx = wi * 32, sy = wj * 32;
  const int w = (128 - sy) < 48 ? (128 - sy) : 48;
  const int h = (128 - sx) < 48 ? (128 - sx) : 48;
  const int Nk = h * w, nch = Nk >> 6;
  const int t = threadIdx.x;
  const int wv = t >> 6, lane = t & 63, g = lane >> 4, lq = lane & 15;

  __shared__ __align__(16) _Float16 kbuf[2][64 * 64]; // [key][64 f16] swizzled (2x8 KB)
  __shared__ __align__(16) _Float16 vbuf[2][64 * 64]; // [ch][64 keys] swizzled (2x8 KB)
  __shared__ __align__(16) _Float16 lp[4][64 * 64];   // per-wave P (f16, 32 KB)

  // Q fragments (B of S^T): B[k=ch][n=q]; wave owns rows r0,r0+1
  const int r0 = sx + qb * 8 + wv * 2;
  f16x8 qf[4][2][2]; // [qt][ks][hi/lo]
  #pragma unroll
  for (int qt = 0; qt < 4; ++qt) {
    int qpix = (r0 + (qt >> 1)) * 128 + sy + (qt & 1) * 16 + lq;
    const _Float16* qp = QT + ((size_t)b * 16384 + qpix) * 128;
    qf[qt][0][0] = *(const f16x8*)(qp + g * 8);
    qf[qt][1][0] = *(const f16x8*)(qp + 32 + g * 8);
    qf[qt][0][1] = *(const f16x8*)(qp + 64 + g * 8);
    qf[qt][1][1] = *(const f16x8*)(qp + 96 + g * 8);
  }

  f32x4 O[4][4]; // O^T acc: m = ch = cht*16 + g*4 + r ; n = q
  #pragma unroll
  for (int qt = 0; qt < 4; ++qt)
    #pragma unroll
    for (int cht = 0; cht < 4; ++cht) O[qt][cht] = (f32x4){0.f, 0.f, 0.f, 0.f};
  float m[4] = {-__builtin_inff(), -__builtin_inff(), -__builtin_inff(), -__builtin_inff()};
  float l[4] = {0.f, 0.f, 0.f, 0.f};

  // ---- DMA stage one 64-key chunk (K 8 KB + V 8 KB) into buffer bu ----
  // K slots: 512 x 16B; slot s=(key,u): LDS linear, source unit u^(key&7).
  // V slots: 512 x 16B; slot s=(ch,u):  LDS linear, source unit u^(ch&7)
  //          (keys su*8..su*8+7, contiguous since 8 | w).
  auto stage = [&](int bu, int kbase) {
    #pragma unroll
    for (int j = 0; j < 2; ++j) {
      int s = j * 256 + t;
      int key = s >> 3, u = s & 7;
      int su = u ^ (key & 7);
      int kg = kbase + key;
      int kr = rowdiv(kg, w), kc = kg - kr * w;
      const _Float16* gp = KT + ((size_t)b * 16384 + (sx + kr) * 128 + sy + kc) * 64 + su * 8;
      dma16(gp, &kbuf[bu][(size_t)(j * 256 + wv * 64) * 8]);
    }
    #pragma unroll
    for (int j = 0; j < 2; ++j) {
      int s = j * 256 + t;
      int chn = s >> 3, u = s & 7;
      int su = u ^ (chn & 7);
      int kg0 = kbase + su * 8;
      int kr = rowdiv(kg0, w);
      int pix = (sx + kr) * 128 + sy + kg0 - kr * w;
      const _Float16* gp = Vc + ((size_t)b * 64 + chn) * 16384 + pix;
      dma16(gp, &vbuf[bu][(size_t)(j * 256 + wv * 64) * 8]);
    }
  };

  stage(0, 0);
  __syncthreads();

  for (int ch = 0; ch < nch; ++ch) {
    const int cur = ch & 1;
    if (ch + 1 < nch) stage(cur ^ 1, (ch + 1) * 64); // prefetch next chunk

    // ---- QK^T: S^T[key][q], K fragments from LDS (swizzled reads) ----
    f32x4 s[4][4]; // [qt][t4]
    #pragma unroll
    for (int qt = 0; qt < 4; ++qt)
      #pragma unroll
      for (int t4 = 0; t4 < 4; ++t4) s[qt][t4] = (f32x4){0.f, 0.f, 0.f, 0.f};
    #pragma unroll
    for (int t4 = 0; t4 < 4; ++t4) {
      int row = t4 * 16 + lq;
      const _Float16* kp = &kbuf[cur][row * 64];
      int sw = row & 7;
      f16x8 kh0 = *(const f16x8*)&kp[(g ^ sw) * 8];
      f16x8 kh1 = *(const f16x8*)&kp[((g + 4) ^ sw) * 8];
      __builtin_amdgcn_s_setprio(1);
      #pragma unroll
      for (int qt = 0; qt < 4; ++qt) {
        s[qt][t4] = mfma16h(kh0, qf[qt][0][0], s[qt][t4]);
        s[qt][t4] = mfma16h(kh0, qf[qt][0][1], s[qt][t4]);
        s[qt][t4] = mfma16h(kh1, qf[qt][1][0], s[qt][t4]);
        s[qt][t4] = mfma16h(kh1, qf[qt][1][1], s[qt][t4]);
      }
      __builtin_amdgcn_s_setprio(0);
    }

    // ---- online softmax (defer-max THR=8, log2 domain) + P (f16) -> lp ----
    #pragma unroll
    for (int qt = 0; qt < 4; ++qt) {
      float cm = -__builtin_inff();
      #pragma unroll
      for (int t4 = 0; t4 < 4; ++t4)
        #pragma unroll
        for (int r = 0; r < 4; ++r) cm = fmaxf(cm, s[qt][t4][r]);
      cm = fmaxf(cm, __shfl_xor(cm, 16));
      cm = fmaxf(cm, __shfl_xor(cm, 32));
      if (__any(cm > m[qt] + 8.0f)) {
        float mnew = fmaxf(m[qt], cm);
        float sc = exp2f(m[qt] - mnew);
        m[qt] = mnew;
        l[qt] *= sc;
        #pragma unroll
        for (int cht = 0; cht < 4; ++cht) O[qt][cht] *= sc;
      }
      float ps = 0.f;
      int rowb = (qt * 16 + lq) * 64;
      #pragma unroll
      for (int t4 = 0; t4 < 4; ++t4) {
        float p0 = exp2f(s[qt][t4][0] - m[qt]);
        float p1 = exp2f(s[qt][t4][1] - m[qt]);
        float p2 = exp2f(s[qt][t4][2] - m[qt]);
        float p3 = exp2f(s[qt][t4][3] - m[qt]);
        ps += (p0 + p1) + (p2 + p3);
        f16x4 ph;
        ph[0] = (_Float16)p0;
        ph[1] = (_Float16)p1;
        ph[2] = (_Float16)p2;
        ph[3] = (_Float16)p3;
        int col = (t4 * 16 + g * 4) ^ ((lq & 7) << 3);
        *(f16x4*)&lp[wv][rowb + col] = ph;
      }
      ps += __shfl_xor(ps, 16);
      ps += __shfl_xor(ps, 32);
      l[qt] += ps;
    }

    // ---- PV: O^T += V^T-frag x P^T-frag, 1-term f16, V from LDS ----
    #pragma unroll
    for (int ks = 0; ks < 2; ++ks) {
      f16x8 vf[4];
      #pragma unroll
      for (int cht = 0; cht < 4; ++cht) {
        int chrow = cht * 16 + lq;
        vf[cht] = *(const f16x8*)&vbuf[cur][chrow * 64 + (((ks * 4 + g) ^ (chrow & 7)) * 8)];
      }
      int pcol = (ks * 32 + g * 8) ^ ((lq & 7) << 3);
      #pragma unroll
      for (int qt = 0; qt < 4; ++qt) {
        int rowb = (qt * 16 + lq) * 64;
        f16x8 pb = *(f16x8*)&lp[wv][rowb + pcol];
        __builtin_amdgcn_s_setprio(1);
        #pragma unroll
        for (int cht = 0; cht < 4; ++cht)
          O[qt][cht] = mfma16h(vf[cht], pb, O[qt][cht]);
        __builtin_amdgcn_s_setprio(0);
      }
    }

    __syncthreads(); // all reads of cur done; next buffer's DMA drained
  }

  // epilogue: out = O/l + residual
  #pragma unroll
  for (int qt = 0; qt < 4; ++qt) {
    float inv = 1.0f / l[qt];
    int qpix = (r0 + (qt >> 1)) * 128 + sy + (qt & 1) * 16 + lq;
    #pragma unroll
    for (int cht = 0; cht < 4; ++cht)
      #pragma unroll
      for (int r = 0; r < 4; ++r) {
        int chn = cht * 16 + g * 4 + r;
        size_t idx = ((size_t)b * 64 + chn) * 16384 + qpix;
        OUT[idx] = O[qt][cht][r] * inv + RES[idx];
      }
  }
}

extern "C" void kernel_launch(void* const* d_in, const int* in_sizes, int n_in,
                              void* d_out, int out_size, void* d_ws, size_t ws_size,
                              hipStream_t stream) {
  const float* x   = (const float*)d_in[0];
  const float* Wq1 = (const float*)d_in[1];
  const float* Wk1 = (const float*)d_in[2];
  const float* Wv1 = (const float*)d_in[3];
  const float* Wq2 = (const float*)d_in[4];
  const float* Wk2 = (const float*)d_in[5];
  const float* Wv2 = (const float*)d_in[6];
  const float* bq1 = (const float*)d_in[7];
  /* bk1 = d_in[8], bk2 = d_in[11]: exactly cancel under softmax */
  const float* bv1 = (const float*)d_in[9];
  const float* bq2 = (const float*)d_in[10];
  const float* bv2 = (const float*)d_in[12];
  float* out = (float*)d_out;

  const size_t IMG = (size_t)8 * 16384;
  _Float16* QT = (_Float16*)d_ws;   // [8][16384][128] (qh|ql)
  _Float16* KT = QT + IMG * 128;    // [8][16384][64]  (kh only)
  _Float16* Vc = KT + IMG * 64;     // [8][64][16384]  (single plane)

  dim3 pgrid(64, 8);
  // layer 1
  proj_kernel<<<pgrid, 256, 0, stream>>>(x, Wq1, Wk1, Wv1, bq1, bv1, QT, KT, Vc);
  attn_kernel<<<512, 256, 0, stream>>>(QT, KT, Vc, x, out);
  // layer 2 (reads layer-1 output from d_out; residual aliases output safely)
  proj_kernel<<<pgrid, 256, 0, stream>>>(out, Wq2, Wk2, Wv2, bq2, bv2, QT, KT, Vc);
  attn_kernel<<<512, 256, 0, stream>>>(QT, KT, Vc, out, out);
}

// Round 21
// 400.699 us; speedup vs baseline: 2.1627x; 1.0119x over previous
//
#include <hip/hip_runtime.h>
#include <hip/hip_bf16.h>

typedef __attribute__((ext_vector_type(8))) __bf16 bf16x8;
typedef __attribute__((ext_vector_type(4))) __bf16 bf16x4;
typedef __attribute__((ext_vector_type(8))) _Float16 f16x8;
typedef __attribute__((ext_vector_type(4))) _Float16 f16x4;
typedef __attribute__((ext_vector_type(4))) float f32x4;

#define LOG2E 1.44269504088896340736f

__device__ inline f32x4 mfma16(bf16x8 a, bf16x8 b, f32x4 c) {
  return __builtin_amdgcn_mfma_f32_16x16x32_bf16(a, b, c, 0, 0, 0);
}
__device__ inline f32x4 mfma16h(f16x8 a, f16x8 b, f32x4 c) {
  return __builtin_amdgcn_mfma_f32_16x16x32_f16(a, b, c, 0, 0, 0);
}

// row/w division for w in {32,48}, kg < 4096
__device__ inline int rowdiv(int kg, int w) {
  return (w == 32) ? (kg >> 5) : ((kg * 43691) >> 21);
}

// async global->LDS DMA, 16B per lane; lds addr is wave-uniform base + lane*16
__device__ __forceinline__ void dma16(const void* g, void* l) {
  __builtin_amdgcn_global_load_lds(
      (const __attribute__((address_space(1))) void*)g,
      (__attribute__((address_space(3))) void*)l, 16, 0, 0);
}

// ------------------------------------------------------------------
// Projection (bf16-pair 3-term GEMM internally, unchanged from R19/R20).
// Outputs: QT f16-pair [B][16384][qh64|ql64], KT f16 single [B][16384][64],
// V f16 single [B][64][16384] ch-major.
// Q scaled by log2(e); bk dropped (softmax-invariant).
// ------------------------------------------------------------------
__global__ __launch_bounds__(256) void proj_kernel(
    const float* __restrict__ X, const float* __restrict__ Wq,
    const float* __restrict__ Wk, const float* __restrict__ Wv,
    const float* __restrict__ bq, const float* __restrict__ bv,
    _Float16* __restrict__ QT, _Float16* __restrict__ KT,
    _Float16* __restrict__ Vc)
{
  const int b = blockIdx.y;
  const int pixbase = blockIdx.x * 256;
  const int t = threadIdx.x;
  __shared__ __align__(16) __bf16 xs[256 * 128]; // [pix][hi64|lo64], row-XOR-swizzled

  { // stage X tile split into hi/lo
    const float* xp = X + (size_t)b * 64 * 16384 + pixbase + t;
    #pragma unroll
    for (int c8 = 0; c8 < 8; ++c8) {
      bf16x8 vh, vl;
      #pragma unroll
      for (int i = 0; i < 8; ++i) {
        float x = xp[(size_t)(c8 * 8 + i) * 16384];
        __bf16 h = (__bf16)x;
        vh[i] = h;
        vl[i] = (__bf16)(x - (float)h);
      }
      int col = (c8 * 8) ^ ((t & 7) << 3);
      *(bf16x8*)&xs[t * 128 + col] = vh;
      *(bf16x8*)&xs[t * 128 + 64 + col] = vl;
    }
  }
  __syncthreads();

  const int wv = t >> 6, lane = t & 63, g = lane >> 4, lq = lane & 15;

  // X as B-fragments: B[k=ci][n=pix], hi and lo
  bf16x8 xf[4][2][2];
  #pragma unroll
  for (int nt = 0; nt < 4; ++nt)
    #pragma unroll
    for (int ks = 0; ks < 2; ++ks) {
      int pixl = wv * 64 + nt * 16 + lq;
      int col = (ks * 32 + g * 8) ^ ((pixl & 7) << 3);
      xf[nt][ks][0] = *(bf16x8*)&xs[pixl * 128 + col];
      xf[nt][ks][1] = *(bf16x8*)&xs[pixl * 128 + 64 + col];
    }

  #pragma unroll
  for (int mat = 0; mat < 3; ++mat) {
    const float* Wm = (mat == 0) ? Wq : (mat == 1) ? Wk : Wv;
    #pragma unroll
    for (int mt = 0; mt < 4; ++mt) {
      // W as A-fragments: A[m=co][k=ci], co = mt*16 + lq, hi/lo split
      bf16x8 wh[2], wl[2];
      #pragma unroll
      for (int ks = 0; ks < 2; ++ks) {
        const float* wp = Wm + (mt * 16 + lq) * 64 + ks * 32 + g * 8;
        f32x4 w0 = *(const f32x4*)wp;
        f32x4 w1 = *(const f32x4*)(wp + 4);
        bf16x8 fh, fl;
        #pragma unroll
        for (int r = 0; r < 4; ++r) {
          __bf16 h0 = (__bf16)w0[r]; fh[r] = h0; fl[r] = (__bf16)(w0[r] - (float)h0);
          __bf16 h1 = (__bf16)w1[r]; fh[4 + r] = h1; fl[4 + r] = (__bf16)(w1[r] - (float)h1);
        }
        wh[ks] = fh; wl[ks] = fl;
      }
      f32x4 binit = {0.f, 0.f, 0.f, 0.f};
      if (mat == 0) binit = *(const f32x4*)(bq + mt * 16 + g * 4);
      if (mat == 2) binit = *(const f32x4*)(bv + mt * 16 + g * 4);
      f32x4 acc[4];
      #pragma unroll
      for (int nt = 0; nt < 4; ++nt) acc[nt] = binit;
      #pragma unroll
      for (int nt = 0; nt < 4; ++nt)
        #pragma unroll
        for (int ks = 0; ks < 2; ++ks) {
          acc[nt] = mfma16(wh[ks], xf[nt][ks][0], acc[nt]);
          acc[nt] = mfma16(wh[ks], xf[nt][ks][1], acc[nt]);
          acc[nt] = mfma16(wl[ks], xf[nt][ks][0], acc[nt]);
        }
      // D layout: m = co = mt*16 + g*4 + r ; n = pix = nt*16 + lq
      #pragma unroll
      for (int nt = 0; nt < 4; ++nt) {
        int pix = pixbase + wv * 64 + nt * 16 + lq;
        if (mat == 2) {
          #pragma unroll
          for (int r = 0; r < 4; ++r)
            Vc[((size_t)b * 64 + mt * 16 + g * 4 + r) * 16384 + pix] = (_Float16)acc[nt][r];
        } else if (mat == 0) {
          f16x4 oh, ol;
          #pragma unroll
          for (int r = 0; r < 4; ++r) {
            float v = acc[nt][r] * LOG2E;
            _Float16 h = (_Float16)v;
            oh[r] = h;
            ol[r] = (_Float16)(v - (float)h);
          }
          _Float16* dst = QT + ((size_t)b * 16384 + pix) * 128 + mt * 16 + g * 4;
          *(f16x4*)dst = oh;
          *(f16x4*)(dst + 64) = ol;
        } else {
          f16x4 oh;
          #pragma unroll
          for (int r = 0; r < 4; ++r) oh[r] = (_Float16)acc[nt][r];
          *(f16x4*)(KT + ((size_t)b * 16384 + pix) * 64 + mt * 16 + g * 4) = oh;
        }
      }
    }
  }
}

// ------------------------------------------------------------------
// Flash attention with DMA-staged single-plane K/V (double-buffered,
// R20-proven) + VALU offload: l computed on the MATRIX pipe via a
// rank-1 ones-MFMA (deletes 64 adds + 8 shfls/chunk from the 47%-busy
// VALU; l also becomes self-consistent with the f16 P numerator), and
// the per-qt max reduce restructured as a v_max3 tree (15 -> ~7 ops).
// QK^T: 2-term f16. PV: 1-term f16. Defer-max THR=8 (log2 domain).
// Block decode: xcd = batch (i&7), windows desc-Nk.
// ------------------------------------------------------------------
__global__ __launch_bounds__(256, 2) void attn_kernel(
    const _Float16* __restrict__ QT, const _Float16* __restrict__ KT,
    const _Float16* __restrict__ Vc, const float* RES, float* OUT)
{
  const int i = blockIdx.x;
  const int b = i & 7;
  const int s_lin = i >> 3;
  const int wo = s_lin >> 2;
  const int qb = s_lin & 3;
  int win;
  {
    int w3 = (wo * 11) >> 5; // wo/3 for wo<9
    win = (wo < 9) ? (wo + w3) : ((wo < 12) ? (3 + ((wo - 9) << 2)) : wo);
  }
  const int wi = win >> 2, wj = win & 3;
  const int sx = wi * 32, sy = wj * 32;
  const int w = (128 - sy) < 48 ? (128 - sy) : 48;
  const int h = (128 - sx) < 48 ? (128 - sx) : 48;
  const int Nk = h * w, nch = Nk >> 6;
  const int t = threadIdx.x;
  const int wv = t >> 6, lane = t & 63, g = lane >> 4, lq = lane & 15;

  __shared__ __align__(16) _Float16 kbuf[2][64 * 64]; // [key][64 f16] swizzled (2x8 KB)
  __shared__ __align__(16) _Float16 vbuf[2][64 * 64]; // [ch][64 keys] swizzled (2x8 KB)
  __shared__ __align__(16) _Float16 lp[4][64 * 64];   // per-wave P (f16, 32 KB)

  // Q fragments (B of S^T): B[k=ch][n=q]; wave owns rows r0,r0+1
  const int r0 = sx + qb * 8 + wv * 2;
  f16x8 qf[4][2][2]; // [qt][ks][hi/lo]
  #pragma unroll
  for (int qt = 0; qt < 4; ++qt) {
    int qpix = (r0 + (qt >> 1)) * 128 + sy + (qt & 1) * 16 + lq;
    const _Float16* qp = QT + ((size_t)b * 16384 + qpix) * 128;
    qf[qt][0][0] = *(const f16x8*)(qp + g * 8);
    qf[qt][1][0] = *(const f16x8*)(qp + 32 + g * 8);
    qf[qt][0][1] = *(const f16x8*)(qp + 64 + g * 8);
    qf[qt][1][1] = *(const f16x8*)(qp + 96 + g * 8);
  }

  // all-ones A-fragment for the l row-sum MFMA
  f16x8 onesv;
  #pragma unroll
  for (int j = 0; j < 8; ++j) onesv[j] = (_Float16)1.0f;

  f32x4 O[4][4];    // O^T acc: m = ch = cht*16 + g*4 + r ; n = q
  f32x4 lacc[4];    // l acc: every element = sum_k P[k][q=lq] (rows identical)
  #pragma unroll
  for (int qt = 0; qt < 4; ++qt) {
    #pragma unroll
    for (int cht = 0; cht < 4; ++cht) O[qt][cht] = (f32x4){0.f, 0.f, 0.f, 0.f};
    lacc[qt] = (f32x4){0.f, 0.f, 0.f, 0.f};
  }
  float m[4] = {-__builtin_inff(), -__builtin_inff(), -__builtin_inff(), -__builtin_inff()};

  // ---- DMA stage one 64-key chunk (K 8 KB + V 8 KB) into buffer bu ----
  auto stage = [&](int bu, int kbase) {
    #pragma unroll
    for (int j = 0; j < 2; ++j) {
      int s = j * 256 + t;
      int key = s >> 3, u = s & 7;
      int su = u ^ (key & 7);
      int kg = kbase + key;
      int kr = rowdiv(kg, w), kc = kg - kr * w;
      const _Float16* gp = KT + ((size_t)b * 16384 + (sx + kr) * 128 + sy + kc) * 64 + su * 8;
      dma16(gp, &kbuf[bu][(size_t)(j * 256 + wv * 64) * 8]);
    }
    #pragma unroll
    for (int j = 0; j < 2; ++j) {
      int s = j * 256 + t;
      int chn = s >> 3, u = s & 7;
      int su = u ^ (chn & 7);
      int kg0 = kbase + su * 8;
      int kr = rowdiv(kg0, w);
      int pix = (sx + kr) * 128 + sy + kg0 - kr * w;
      const _Float16* gp = Vc + ((size_t)b * 64 + chn) * 16384 + pix;
      dma16(gp, &vbuf[bu][(size_t)(j * 256 + wv * 64) * 8]);
    }
  };

  stage(0, 0);
  __syncthreads();

  for (int ch = 0; ch < nch; ++ch) {
    const int cur = ch & 1;
    if (ch + 1 < nch) stage(cur ^ 1, (ch + 1) * 64); // prefetch next chunk

    // ---- QK^T: S^T[key][q], K fragments from LDS (swizzled reads) ----
    f32x4 s[4][4]; // [qt][t4]
    #pragma unroll
    for (int qt = 0; qt < 4; ++qt)
      #pragma unroll
      for (int t4 = 0; t4 < 4; ++t4) s[qt][t4] = (f32x4){0.f, 0.f, 0.f, 0.f};
    #pragma unroll
    for (int t4 = 0; t4 < 4; ++t4) {
      int row = t4 * 16 + lq;
      const _Float16* kp = &kbuf[cur][row * 64];
      int sw = row & 7;
      f16x8 kh0 = *(const f16x8*)&kp[(g ^ sw) * 8];
      f16x8 kh1 = *(const f16x8*)&kp[((g + 4) ^ sw) * 8];
      __builtin_amdgcn_s_setprio(1);
      #pragma unroll
      for (int qt = 0; qt < 4; ++qt) {
        s[qt][t4] = mfma16h(kh0, qf[qt][0][0], s[qt][t4]);
        s[qt][t4] = mfma16h(kh0, qf[qt][0][1], s[qt][t4]);
        s[qt][t4] = mfma16h(kh1, qf[qt][1][0], s[qt][t4]);
        s[qt][t4] = mfma16h(kh1, qf[qt][1][1], s[qt][t4]);
      }
      __builtin_amdgcn_s_setprio(0);
    }

    // ---- softmax: defer-max (THR=8), max3-tree reduce, P (f16) -> lp ----
    #pragma unroll
    for (int qt = 0; qt < 4; ++qt) {
      // v_max3 tree over the 16 lane-local scores
      float a0 = fmaxf(fmaxf(s[qt][0][0], s[qt][0][1]), s[qt][0][2]);
      float a1 = fmaxf(fmaxf(s[qt][0][3], s[qt][1][0]), s[qt][1][1]);
      float a2 = fmaxf(fmaxf(s[qt][1][2], s[qt][1][3]), s[qt][2][0]);
      float a3 = fmaxf(fmaxf(s[qt][2][1], s[qt][2][2]), s[qt][2][3]);
      float a4 = fmaxf(fmaxf(s[qt][3][0], s[qt][3][1]), s[qt][3][2]);
      float cm = fmaxf(fmaxf(fmaxf(a0, a1), fmaxf(a2, a3)),
                       fmaxf(a4, s[qt][3][3]));
      cm = fmaxf(cm, __shfl_xor(cm, 16));
      cm = fmaxf(cm, __shfl_xor(cm, 32));
      if (__any(cm > m[qt] + 8.0f)) {
        float mnew = fmaxf(m[qt], cm);
        float sc = exp2f(m[qt] - mnew);
        m[qt] = mnew;
        lacc[qt] *= sc;
        #pragma unroll
        for (int cht = 0; cht < 4; ++cht) O[qt][cht] *= sc;
      }
      int rowb = (qt * 16 + lq) * 64;
      #pragma unroll
      for (int t4 = 0; t4 < 4; ++t4) {
        f16x4 ph;
        ph[0] = (_Float16)exp2f(s[qt][t4][0] - m[qt]);
        ph[1] = (_Float16)exp2f(s[qt][t4][1] - m[qt]);
        ph[2] = (_Float16)exp2f(s[qt][t4][2] - m[qt]);
        ph[3] = (_Float16)exp2f(s[qt][t4][3] - m[qt]);
        int col = (t4 * 16 + g * 4) ^ ((lq & 7) << 3);
        *(f16x4*)&lp[wv][rowb + col] = ph;
      }
    }

    // ---- PV + l: O^T += V^T x P^T; lacc += ones x P^T (row-sum MFMA) ----
    #pragma unroll
    for (int ks = 0; ks < 2; ++ks) {
      f16x8 vf[4];
      #pragma unroll
      for (int cht = 0; cht < 4; ++cht) {
        int chrow = cht * 16 + lq;
        vf[cht] = *(const f16x8*)&vbuf[cur][chrow * 64 + (((ks * 4 + g) ^ (chrow & 7)) * 8)];
      }
      int pcol = (ks * 32 + g * 8) ^ ((lq & 7) << 3);
      #pragma unroll
      for (int qt = 0; qt < 4; ++qt) {
        int rowb = (qt * 16 + lq) * 64;
        f16x8 pb = *(f16x8*)&lp[wv][rowb + pcol];
        __builtin_amdgcn_s_setprio(1);
        lacc[qt] = mfma16h(onesv, pb, lacc[qt]);
        #pragma unroll
        for (int cht = 0; cht < 4; ++cht)
          O[qt][cht] = mfma16h(vf[cht], pb, O[qt][cht]);
        __builtin_amdgcn_s_setprio(0);
      }
    }

    __syncthreads(); // all reads of cur done; next buffer's DMA drained
  }

  // epilogue: out = O/l + residual (l broadcast in every lacc element)
  #pragma unroll
  for (int qt = 0; qt < 4; ++qt) {
    float inv = 1.0f / lacc[qt][0];
    int qpix = (r0 + (qt >> 1)) * 128 + sy + (qt & 1) * 16 + lq;
    #pragma unroll
    for (int cht = 0; cht < 4; ++cht)
      #pragma unroll
      for (int r = 0; r < 4; ++r) {
        int chn = cht * 16 + g * 4 + r;
        size_t idx = ((size_t)b * 64 + chn) * 16384 + qpix;
        OUT[idx] = O[qt][cht][r] * inv + RES[idx];
      }
  }
}

extern "C" void kernel_launch(void* const* d_in, const int* in_sizes, int n_in,
                              void* d_out, int out_size, void* d_ws, size_t ws_size,
                              hipStream_t stream) {
  const float* x   = (const float*)d_in[0];
  const float* Wq1 = (const float*)d_in[1];
  const float* Wk1 = (const float*)d_in[2];
  const float* Wv1 = (const float*)d_in[3];
  const float* Wq2 = (const float*)d_in[4];
  const float* Wk2 = (const float*)d_in[5];
  const float* Wv2 = (const float*)d_in[6];
  const float* bq1 = (const float*)d_in[7];
  /* bk1 = d_in[8], bk2 = d_in[11]: exactly cancel under softmax */
  const float* bv1 = (const float*)d_in[9];
  const float* bq2 = (const float*)d_in[10];
  const float* bv2 = (const float*)d_in[12];
  float* out = (float*)d_out;

  const size_t IMG = (size_t)8 * 16384;
  _Float16* QT = (_Float16*)d_ws;   // [8][16384][128] (qh|ql)
  _Float16* KT = QT + IMG * 128;    // [8][16384][64]  (kh only)
  _Float16* Vc = KT + IMG * 64;     // [8][64][16384]  (single plane)

  dim3 pgrid(64, 8);
  // layer 1
  proj_kernel<<<pgrid, 256, 0, stream>>>(x, Wq1, Wk1, Wv1, bq1, bv1, QT, KT, Vc);
  attn_kernel<<<512, 256, 0, stream>>>(QT, KT, Vc, x, out);
  // layer 2 (reads layer-1 output from d_out; residual aliases output safely)
  proj_kernel<<<pgrid, 256, 0, stream>>>(out, Wq2, Wk2, Wv2, bq2, bv2, QT, KT, Vc);
  attn_kernel<<<512, 256, 0, stream>>>(QT, KT, Vc, out, out);
}